// Round 2
// baseline (544.043 us; speedup 1.0000x reference)
//
#include <hip/hip_runtime.h>

// SelfAttentionWithLeads v2: split-P design.
// B=32, H=12, W=256, C=256, SPLIT=3 -> hs=4, N=1024, d_qk=96, d_v=768.
//
// d_ws layout (bytes), total 130,187,264 (~130 MB):
//   Wt   @ 0         : [320][256] bf16  (Wf|Wg|Wh transposed)     163,840
//   f_fl @ 163840    : [32][1024][96] bf16                      6,291,456
//   g_fl @ 6455296   : [32][1024][96] bf16                      6,291,456
//   h_t  @ 12746752  : [32][768][1024] bf16 (pre-transposed)   50,331,648
//   P    @ 63078400  : [32][1024][1024] bf16 softmax probs     67,108,864

typedef __bf16 bf16x8 __attribute__((ext_vector_type(8)));
typedef float f32x4 __attribute__((ext_vector_type(4)));

#define MFMA16 __builtin_amdgcn_mfma_f32_16x16x32_bf16

__device__ __forceinline__ short f2bf(float f) {
    unsigned u = __builtin_bit_cast(unsigned, f);
    u += 0x7fffu + ((u >> 16) & 1u);   // round-to-nearest-even
    return (short)(u >> 16);
}
__device__ __forceinline__ unsigned pack2bf(float a, float b) {
    return ((unsigned)(unsigned short)f2bf(a)) |
           (((unsigned)(unsigned short)f2bf(b)) << 16);
}

// ---------------------------------------------------------------- weights ---
__global__ __launch_bounds__(256) void wt_kernel(const float* __restrict__ Wf,
                                                 const float* __restrict__ Wg,
                                                 const float* __restrict__ Wh,
                                                 short* __restrict__ Wt) {
    int t = blockIdx.x * 256 + threadIdx.x;   // 0..81919
    int j = t >> 8, k = t & 255;
    float v;
    if (j < 32)      v = Wf[k * 32 + j];
    else if (j < 64) v = Wg[k * 32 + (j - 32)];
    else             v = Wh[k * 256 + (j - 64)];
    Wt[j * 256 + k] = f2bf(v);
}

// ------------------------------------------------------------- projections --
// Block = 64 consecutive pixels. Operand orientation chosen per output so the
// C-tile's 4 row-consecutive values pack into one 8B store.
__global__ __launch_bounds__(256) void proj_kernel(const float* __restrict__ x,
                                                   const short* __restrict__ Wt,
                                                   short* __restrict__ f_fl,
                                                   short* __restrict__ g_fl,
                                                   short* __restrict__ h_t) {
    const int tid = threadIdx.x;
    const int P0  = blockIdx.x * 64;
    const int b   = P0 / 3072;
    const int rem = P0 % 3072;
    const int hh  = rem >> 8;
    const int wbase = rem & 255;
    const int lead = hh >> 2, hsi = hh & 3;
    const int nbase = hsi * 256 + wbase;

    __shared__ __align__(16) short xs[64][264];

    const float4* xv = (const float4*)(x + (size_t)P0 * 256);
    #pragma unroll
    for (int i = 0; i < 16; ++i) {
        int idx = i * 256 + tid;
        float4 v = xv[idx];
        int pix = idx >> 6;
        int col = (idx & 63) * 4;
        *(short4*)&xs[pix][col] =
            make_short4(f2bf(v.x), f2bf(v.y), f2bf(v.z), f2bf(v.w));
    }
    __syncthreads();

    const int lane = tid & 63, wv = tid >> 6;
    const int quad = lane >> 4, l15 = lane & 15;

    // ---- phase 1: f,g transposed orientation (rows = channels j) ----
    // wave wv covers j-rows wv*16..+15 of Wt[0..63] (f then g), all 64 pix.
    {
        const int jrow = wv * 16 + l15;
        f32x4 acc[4] = {};
        #pragma unroll
        for (int ki = 0; ki < 8; ++ki) {
            bf16x8 a = *(const bf16x8*)&Wt[jrow * 256 + ki * 32 + quad * 8];
            #pragma unroll
            for (int pt = 0; pt < 4; ++pt) {
                bf16x8 bb = *(const bf16x8*)&xs[pt * 16 + l15][ki * 32 + quad * 8];
                acc[pt] = MFMA16(a, bb, acc[pt], 0, 0, 0);
            }
        }
        short* dst = (wv < 2) ? f_fl : g_fl;
        const int jloc = (wv & 1) * 16 + quad * 4;
        #pragma unroll
        for (int pt = 0; pt < 4; ++pt) {
            int n = nbase + pt * 16 + l15;
            *(short4*)&dst[((size_t)b * 1024 + n) * 96 + lead * 32 + jloc] =
                make_short4(f2bf(acc[pt][0]), f2bf(acc[pt][1]),
                            f2bf(acc[pt][2]), f2bf(acc[pt][3]));
        }
    }

    // ---- phase 2: h (rows = pixels, cols = out-channel cc) ----
    // wave wv covers cc = wv*64..+63, all 64 pix.
    {
        f32x4 acc[4][4] = {};
        #pragma unroll
        for (int ki = 0; ki < 8; ++ki) {
            bf16x8 a[4], bb[4];
            #pragma unroll
            for (int pt = 0; pt < 4; ++pt)
                a[pt] = *(const bf16x8*)&xs[pt * 16 + l15][ki * 32 + quad * 8];
            #pragma unroll
            for (int ct = 0; ct < 4; ++ct)
                bb[ct] = *(const bf16x8*)&Wt[(64 + wv * 64 + ct * 16 + l15) * 256 + ki * 32 + quad * 8];
            #pragma unroll
            for (int pt = 0; pt < 4; ++pt)
                #pragma unroll
                for (int ct = 0; ct < 4; ++ct)
                    acc[pt][ct] = MFMA16(a[pt], bb[ct], acc[pt][ct], 0, 0, 0);
        }
        #pragma unroll
        for (int pt = 0; pt < 4; ++pt)
            #pragma unroll
            for (int ct = 0; ct < 4; ++ct) {
                int cc = wv * 64 + ct * 16 + l15;
                size_t base = ((size_t)b * 768 + lead * 256 + cc) * 1024
                              + nbase + pt * 16 + quad * 4;
                *(short4*)&h_t[base] =
                    make_short4(f2bf(acc[pt][ct][0]), f2bf(acc[pt][ct][1]),
                                f2bf(acc[pt][ct][2]), f2bf(acc[pt][ct][3]));
            }
    }
}

// ------------------------------------------------- softmax probability gen --
// Transposed-S orientation: St = MFMA(A=f(keys as rows), B=g(qrows as cols)).
// Lane (quad,l15) holds P^T[key=quad*4+r][qrow=l15] -> stats are per-lane
// online (no in-loop shuffles); P[qrow][key] packs to 8B global stores.
__global__ __launch_bounds__(256) void pgen_kernel(const short* __restrict__ f_fl,
                                                   const short* __restrict__ g_fl,
                                                   short* __restrict__ P) {
    const int qb = blockIdx.x, b = blockIdx.y;
    const int tid = threadIdx.x, lane = tid & 63, wv = tid >> 6;
    const int quad = lane >> 4, l15 = lane & 15;
    const int qrow = qb * 64 + wv * 16 + l15;     // this lane's q column
    const short* fB = f_fl + (size_t)b * 1024 * 96;
    const short* gB = g_fl + (size_t)b * 1024 * 96;

    bf16x8 ga[3];
    #pragma unroll
    for (int ki = 0; ki < 3; ++ki)
        ga[ki] = *(const bf16x8*)&gB[qrow * 96 + ki * 32 + quad * 8];

    // pass 1: per-lane online max/sum over this lane's key subset
    float m = -1e30f, l = 0.f;
    for (int mt = 0; mt < 32; ++mt) {
        int m0 = mt * 32;
        f32x4 st[2] = {};
        #pragma unroll
        for (int mf = 0; mf < 2; ++mf)
            #pragma unroll
            for (int ki = 0; ki < 3; ++ki) {
                bf16x8 fb = *(const bf16x8*)&fB[(m0 + mf * 16 + l15) * 96 + ki * 32 + quad * 8];
                st[mf] = MFMA16(fb, ga[ki], st[mf], 0, 0, 0);
            }
        float vmax = st[0][0];
        #pragma unroll
        for (int r = 1; r < 4; ++r) vmax = fmaxf(vmax, st[0][r]);
        #pragma unroll
        for (int r = 0; r < 4; ++r) vmax = fmaxf(vmax, st[1][r]);
        float nm = fmaxf(m, vmax);
        float e = 0.f;
        #pragma unroll
        for (int mf = 0; mf < 2; ++mf)
            #pragma unroll
            for (int r = 0; r < 4; ++r) e += __expf(st[mf][r] - nm);
        l = l * __expf(m - nm) + e;
        m = nm;
    }
    // cross-quad combine (lanes l15, l15+16, l15+32, l15+48 share qrow)
    #pragma unroll
    for (int d = 16; d < 64; d <<= 1) {
        float mo = __shfl_xor(m, d);
        float lo = __shfl_xor(l, d);
        float nm = fmaxf(m, mo);
        l = l * __expf(m - nm) + lo * __expf(mo - nm);
        m = nm;
    }
    const float li = 1.0f / l;

    // pass 2: recompute St (identical MFMA order), exp, pack, store P
    short* Pq = P + ((size_t)b * 1024 + qrow) * 1024;
    for (int mt = 0; mt < 32; ++mt) {
        int m0 = mt * 32;
        f32x4 st[2] = {};
        #pragma unroll
        for (int mf = 0; mf < 2; ++mf)
            #pragma unroll
            for (int ki = 0; ki < 3; ++ki) {
                bf16x8 fb = *(const bf16x8*)&fB[(m0 + mf * 16 + l15) * 96 + ki * 32 + quad * 8];
                st[mf] = MFMA16(fb, ga[ki], st[mf], 0, 0, 0);
            }
        #pragma unroll
        for (int mf = 0; mf < 2; ++mf) {
            uint2 w;
            w.x = pack2bf(__expf(st[mf][0] - m) * li, __expf(st[mf][1] - m) * li);
            w.y = pack2bf(__expf(st[mf][2] - m) * li, __expf(st[mf][3] - m) * li);
            *(uint2*)&Pq[m0 + mf * 16 + quad * 4] = w;
        }
    }
}

// --------------------------------------------------------------- PV GEMM ----
// O = P * H^T. grid (vb=4, qb=8, b=32), wave = 32 q-rows x 192 v-cols.
// No LDS, no exp: A-frags (P rows) and B-frags (h_t rows) direct from global,
// hv double-buffered so loads stay in flight across MFMA blocks.
__global__ __launch_bounds__(256, 2) void gemm_kernel(const short* __restrict__ P,
                                                      const short* __restrict__ h_t,
                                                      const float* __restrict__ x,
                                                      const float* __restrict__ gammap,
                                                      float* __restrict__ out) {
    const int vb = blockIdx.x, qb = blockIdx.y, b = blockIdx.z;
    const int tid = threadIdx.x, lane = tid & 63, wv = tid >> 6;
    const int quad = lane >> 4, l15 = lane & 15;
    const int wq = qb * 128 + wv * 32;
    const short* Pb = P + (size_t)b * 1024 * 1024;
    const short* hB = h_t + (size_t)b * 768 * 1024;

    f32x4 o[2][12] = {};
    bf16x8 hvb[2][12];
    bf16x8 pa[2];

    // hv base addresses: vc = vb*192 + g*16 + l15, key offset quad*8
    const short* hp = hB + (size_t)(vb * 192 + l15) * 1024 + quad * 8;

    #pragma unroll
    for (int g = 0; g < 12; ++g)
        hvb[0][g] = *(const bf16x8*)&hp[(size_t)g * 16 * 1024];

    #pragma unroll 2
    for (int mt = 0; mt < 32; ++mt) {
        const int m0 = mt * 32;
        const int cur = mt & 1, nxt = cur ^ 1;
        #pragma unroll
        for (int qf = 0; qf < 2; ++qf)
            pa[qf] = *(const bf16x8*)&Pb[(size_t)(wq + qf * 16 + l15) * 1024 + m0 + quad * 8];
        if (mt < 31) {
            #pragma unroll
            for (int g = 0; g < 12; ++g)
                hvb[nxt][g] = *(const bf16x8*)&hp[(size_t)g * 16 * 1024 + m0 + 32];
        }
        #pragma unroll
        for (int g = 0; g < 12; ++g) {
            o[0][g] = MFMA16(pa[0], hvb[cur][g], o[0][g], 0, 0, 0);
            o[1][g] = MFMA16(pa[1], hvb[cur][g], o[1][g], 0, 0, 0);
        }
    }

    const float gamma = gammap[0];
    #pragma unroll
    for (int qf = 0; qf < 2; ++qf)
        #pragma unroll
        for (int g = 0; g < 12; ++g) {
            int vc = vb * 192 + g * 16 + l15;
            int lead = vc >> 8, c = vc & 255;
            #pragma unroll
            for (int r = 0; r < 4; ++r) {
                int n = wq + qf * 16 + quad * 4 + r;
                int hsi = n >> 8, w_ = n & 255;
                size_t idx = (((size_t)b * 12 + lead * 4 + hsi) * 256 + w_) * 256 + c;
                out[idx] = gamma * o[qf][g][r] + x[idx];
            }
        }
}

// ------------------------------------------------------------------ launch --
extern "C" void kernel_launch(void* const* d_in, const int* in_sizes, int n_in,
                              void* d_out, int out_size, void* d_ws, size_t ws_size,
                              hipStream_t stream) {
    const float* x     = (const float*)d_in[0];
    const float* Wf    = (const float*)d_in[1];
    const float* Wg    = (const float*)d_in[2];
    const float* Wh    = (const float*)d_in[3];
    const float* gamma = (const float*)d_in[4];
    float* out = (float*)d_out;

    char* ws = (char*)d_ws;
    short* Wt   = (short*)(ws + 0);
    short* f_fl = (short*)(ws + 163840);
    short* g_fl = (short*)(ws + 6455296);
    short* h_t  = (short*)(ws + 12746752);
    short* P    = (short*)(ws + 63078400);

    wt_kernel<<<dim3(320), dim3(256), 0, stream>>>(Wf, Wg, Wh, Wt);
    proj_kernel<<<dim3(1536), dim3(256), 0, stream>>>(x, Wt, f_fl, g_fl, h_t);
    pgen_kernel<<<dim3(16, 32), dim3(256), 0, stream>>>(f_fl, g_fl, P);
    gemm_kernel<<<dim3(4, 8, 32), dim3(256), 0, stream>>>(P, h_t, x, gamma, out);
}

// Round 3
// 450.669 us; speedup vs baseline: 1.2072x; 1.2072x over previous
//
#include <hip/hip_runtime.h>

// SelfAttentionWithLeads v3: split-P + m97-style tiled PV GEMM.
// B=32, H=12, W=256, C=256, SPLIT=3 -> hs=4, N=1024, d_qk=96, d_v=768.
//
// d_ws layout (bytes), total 130,187,264 (~130 MB):
//   Wt   @ 0         : [320][256] bf16  (Wf|Wg|Wh transposed)     163,840
//   f_fl @ 163840    : [32][1024][96] bf16                      6,291,456
//   g_fl @ 6455296   : [32][1024][96] bf16                      6,291,456
//   h_t  @ 12746752  : [32][768][1024] bf16 (pre-transposed)   50,331,648
//   P    @ 63078400  : [32][1024][1024] bf16 softmax probs     67,108,864

typedef __bf16 bf16x8 __attribute__((ext_vector_type(8)));
typedef float f32x4 __attribute__((ext_vector_type(4)));

#define MFMA16 __builtin_amdgcn_mfma_f32_16x16x32_bf16

__device__ __forceinline__ short f2bf(float f) {
    unsigned u = __builtin_bit_cast(unsigned, f);
    u += 0x7fffu + ((u >> 16) & 1u);   // round-to-nearest-even
    return (short)(u >> 16);
}
__device__ __forceinline__ unsigned pack2bf(float a, float b) {
    return ((unsigned)(unsigned short)f2bf(a)) |
           (((unsigned)(unsigned short)f2bf(b)) << 16);
}
__device__ __forceinline__ void gload_lds16(const short* g, short* l) {
    __builtin_amdgcn_global_load_lds(
        (const __attribute__((address_space(1))) unsigned int*)g,
        (__attribute__((address_space(3))) unsigned int*)l, 16, 0, 0);
}

// ---------------------------------------------------------------- weights ---
__global__ __launch_bounds__(256) void wt_kernel(const float* __restrict__ Wf,
                                                 const float* __restrict__ Wg,
                                                 const float* __restrict__ Wh,
                                                 short* __restrict__ Wt) {
    int t = blockIdx.x * 256 + threadIdx.x;   // 0..81919
    int j = t >> 8, k = t & 255;
    float v;
    if (j < 32)      v = Wf[k * 32 + j];
    else if (j < 64) v = Wg[k * 32 + (j - 32)];
    else             v = Wh[k * 256 + (j - 64)];
    Wt[j * 256 + k] = f2bf(v);
}

// ------------------------------------------------------------- projections --
// Block = 64 consecutive pixels. Operand orientation chosen per output so the
// C-tile's 4 row-consecutive values pack into one 8B store.
__global__ __launch_bounds__(256) void proj_kernel(const float* __restrict__ x,
                                                   const short* __restrict__ Wt,
                                                   short* __restrict__ f_fl,
                                                   short* __restrict__ g_fl,
                                                   short* __restrict__ h_t) {
    const int tid = threadIdx.x;
    const int P0  = blockIdx.x * 64;
    const int b   = P0 / 3072;
    const int rem = P0 % 3072;
    const int hh  = rem >> 8;
    const int wbase = rem & 255;
    const int lead = hh >> 2, hsi = hh & 3;
    const int nbase = hsi * 256 + wbase;

    __shared__ __align__(16) short xs[64][264];

    const float4* xv = (const float4*)(x + (size_t)P0 * 256);
    #pragma unroll
    for (int i = 0; i < 16; ++i) {
        int idx = i * 256 + tid;
        float4 v = xv[idx];
        int pix = idx >> 6;
        int col = (idx & 63) * 4;
        *(short4*)&xs[pix][col] =
            make_short4(f2bf(v.x), f2bf(v.y), f2bf(v.z), f2bf(v.w));
    }
    __syncthreads();

    const int lane = tid & 63, wv = tid >> 6;
    const int quad = lane >> 4, l15 = lane & 15;

    // ---- phase 1: f,g transposed orientation (rows = channels j) ----
    {
        const int jrow = wv * 16 + l15;
        f32x4 acc[4] = {};
        #pragma unroll
        for (int ki = 0; ki < 8; ++ki) {
            bf16x8 a = *(const bf16x8*)&Wt[jrow * 256 + ki * 32 + quad * 8];
            #pragma unroll
            for (int pt = 0; pt < 4; ++pt) {
                bf16x8 bb = *(const bf16x8*)&xs[pt * 16 + l15][ki * 32 + quad * 8];
                acc[pt] = MFMA16(a, bb, acc[pt], 0, 0, 0);
            }
        }
        short* dst = (wv < 2) ? f_fl : g_fl;
        const int jloc = (wv & 1) * 16 + quad * 4;
        #pragma unroll
        for (int pt = 0; pt < 4; ++pt) {
            int n = nbase + pt * 16 + l15;
            *(short4*)&dst[((size_t)b * 1024 + n) * 96 + lead * 32 + jloc] =
                make_short4(f2bf(acc[pt][0]), f2bf(acc[pt][1]),
                            f2bf(acc[pt][2]), f2bf(acc[pt][3]));
        }
    }

    // ---- phase 2: h (rows = pixels, cols = out-channel cc) ----
    {
        f32x4 acc[4][4] = {};
        #pragma unroll
        for (int ki = 0; ki < 8; ++ki) {
            bf16x8 a[4], bb[4];
            #pragma unroll
            for (int pt = 0; pt < 4; ++pt)
                a[pt] = *(const bf16x8*)&xs[pt * 16 + l15][ki * 32 + quad * 8];
            #pragma unroll
            for (int ct = 0; ct < 4; ++ct)
                bb[ct] = *(const bf16x8*)&Wt[(64 + wv * 64 + ct * 16 + l15) * 256 + ki * 32 + quad * 8];
            #pragma unroll
            for (int pt = 0; pt < 4; ++pt)
                #pragma unroll
                for (int ct = 0; ct < 4; ++ct)
                    acc[pt][ct] = MFMA16(a[pt], bb[ct], acc[pt][ct], 0, 0, 0);
        }
        #pragma unroll
        for (int pt = 0; pt < 4; ++pt)
            #pragma unroll
            for (int ct = 0; ct < 4; ++ct) {
                int cc = wv * 64 + ct * 16 + l15;
                size_t base = ((size_t)b * 768 + lead * 256 + cc) * 1024
                              + nbase + pt * 16 + quad * 4;
                *(short4*)&h_t[base] =
                    make_short4(f2bf(acc[pt][ct][0]), f2bf(acc[pt][ct][1]),
                                f2bf(acc[pt][ct][2]), f2bf(acc[pt][ct][3]));
            }
    }
}

// ------------------------------------------------- softmax probability gen --
__global__ __launch_bounds__(256) void pgen_kernel(const short* __restrict__ f_fl,
                                                   const short* __restrict__ g_fl,
                                                   short* __restrict__ P) {
    const int qb = blockIdx.x, b = blockIdx.y;
    const int tid = threadIdx.x, lane = tid & 63, wv = tid >> 6;
    const int quad = lane >> 4, l15 = lane & 15;
    const int qrow = qb * 64 + wv * 16 + l15;
    const short* fB = f_fl + (size_t)b * 1024 * 96;
    const short* gB = g_fl + (size_t)b * 1024 * 96;

    bf16x8 ga[3];
    #pragma unroll
    for (int ki = 0; ki < 3; ++ki)
        ga[ki] = *(const bf16x8*)&gB[qrow * 96 + ki * 32 + quad * 8];

    float m = -1e30f, l = 0.f;
    for (int mt = 0; mt < 32; ++mt) {
        int m0 = mt * 32;
        f32x4 st[2] = {};
        #pragma unroll
        for (int mf = 0; mf < 2; ++mf)
            #pragma unroll
            for (int ki = 0; ki < 3; ++ki) {
                bf16x8 fb = *(const bf16x8*)&fB[(m0 + mf * 16 + l15) * 96 + ki * 32 + quad * 8];
                st[mf] = MFMA16(fb, ga[ki], st[mf], 0, 0, 0);
            }
        float vmax = st[0][0];
        #pragma unroll
        for (int r = 1; r < 4; ++r) vmax = fmaxf(vmax, st[0][r]);
        #pragma unroll
        for (int r = 0; r < 4; ++r) vmax = fmaxf(vmax, st[1][r]);
        float nm = fmaxf(m, vmax);
        float e = 0.f;
        #pragma unroll
        for (int mf = 0; mf < 2; ++mf)
            #pragma unroll
            for (int r = 0; r < 4; ++r) e += __expf(st[mf][r] - nm);
        l = l * __expf(m - nm) + e;
        m = nm;
    }
    #pragma unroll
    for (int d = 16; d < 64; d <<= 1) {
        float mo = __shfl_xor(m, d);
        float lo = __shfl_xor(l, d);
        float nm = fmaxf(m, mo);
        l = l * __expf(m - nm) + lo * __expf(mo - nm);
        m = nm;
    }
    const float li = 1.0f / l;

    short* Pq = P + ((size_t)b * 1024 + qrow) * 1024;
    for (int mt = 0; mt < 32; ++mt) {
        int m0 = mt * 32;
        f32x4 st[2] = {};
        #pragma unroll
        for (int mf = 0; mf < 2; ++mf)
            #pragma unroll
            for (int ki = 0; ki < 3; ++ki) {
                bf16x8 fb = *(const bf16x8*)&fB[(m0 + mf * 16 + l15) * 96 + ki * 32 + quad * 8];
                st[mf] = MFMA16(fb, ga[ki], st[mf], 0, 0, 0);
            }
        #pragma unroll
        for (int mf = 0; mf < 2; ++mf) {
            uint2 w;
            w.x = pack2bf(__expf(st[mf][0] - m) * li, __expf(st[mf][1] - m) * li);
            w.y = pack2bf(__expf(st[mf][2] - m) * li, __expf(st[mf][3] - m) * li);
            *(uint2*)&Pq[m0 + mf * 16 + quad * 4] = w;
        }
    }
}

// --------------------------------------------------------------- PV GEMM ----
// O^T = H_t * P^T per batch: A = h_t rows (M=768 v-cols), B = P rows
// (N=1024 q-rows), K=1024 keys. m97 structure: 128x128 tile, BK=32,
// global_load_lds width 16, 4 waves in 2x2, 16 MFMA/wave/K-step.
// Epilogue: lane's 4 acc regs = 4 consecutive channels -> float4 store.
__global__ __launch_bounds__(256, 2) void gemm_kernel(const short* __restrict__ P,
                                                      const short* __restrict__ h_t,
                                                      const float* __restrict__ x,
                                                      const float* __restrict__ gammap,
                                                      float* __restrict__ out) {
    const int mt = blockIdx.x, nt = blockIdx.y, b = blockIdx.z;
    const int tid = threadIdx.x, lane = tid & 63, wv = tid >> 6;
    const int quad = lane >> 4, l15 = lane & 15;
    const int wm = (wv & 1) * 64, wn = (wv >> 1) * 64;

    __shared__ __align__(16) short As[128 * 32];
    __shared__ __align__(16) short Bs[128 * 32];

    const short* hB = h_t + ((size_t)b * 768 + mt * 128) * 1024;
    const short* Pb = P + ((size_t)b * 1024 + nt * 128) * 1024;

    // staging: wave wv, issue j -> rows j*64 + wv*16 .. +15; lane i covers
    // row (i>>2), 16B chunk (i&3). LDS dst = base + lane*16 (contiguous).
    const int srow = wv * 16 + (lane >> 2);
    const int scol = (lane & 3) * 8;
    const short* gA0 = hB + (size_t)srow * 1024 + scol;
    const short* gA1 = hB + (size_t)(srow + 64) * 1024 + scol;
    const short* gB0 = Pb + (size_t)srow * 1024 + scol;
    const short* gB1 = Pb + (size_t)(srow + 64) * 1024 + scol;
    short* lA0 = &As[srow * 32 + scol];
    short* lA1 = &As[(srow + 64) * 32 + scol];
    short* lB0 = &Bs[srow * 32 + scol];
    short* lB1 = &Bs[(srow + 64) * 32 + scol];

    f32x4 acc[4][4] = {};

    for (int kt = 0; kt < 32; ++kt) {
        const int k0 = kt * 32;
        gload_lds16(gA0 + k0, lA0);
        gload_lds16(gA1 + k0, lA1);
        gload_lds16(gB0 + k0, lB0);
        gload_lds16(gB1 + k0, lB1);
        __syncthreads();
        bf16x8 a[4], bb[4];
        #pragma unroll
        for (int i = 0; i < 4; ++i)
            a[i] = *(const bf16x8*)&As[(wm + i * 16 + l15) * 32 + quad * 8];
        #pragma unroll
        for (int j = 0; j < 4; ++j)
            bb[j] = *(const bf16x8*)&Bs[(wn + j * 16 + l15) * 32 + quad * 8];
        #pragma unroll
        for (int i = 0; i < 4; ++i)
            #pragma unroll
            for (int j = 0; j < 4; ++j)
                acc[i][j] = MFMA16(a[i], bb[j], acc[i][j], 0, 0, 0);
        __syncthreads();
    }

    const float gamma = gammap[0];
    #pragma unroll
    for (int i = 0; i < 4; ++i)
        #pragma unroll
        for (int j = 0; j < 4; ++j) {
            int vc = mt * 128 + wm + i * 16 + quad * 4;   // 4 consecutive channels
            int qrow = nt * 128 + wn + j * 16 + l15;
            int lead = vc >> 8, c = vc & 255;
            int hsi = qrow >> 8, w_ = qrow & 255;
            size_t idx = (((size_t)b * 12 + lead * 4 + hsi) * 256 + w_) * 256 + c;
            float4 xv = *(const float4*)&x[idx];
            float4 ov;
            ov.x = gamma * acc[i][j][0] + xv.x;
            ov.y = gamma * acc[i][j][1] + xv.y;
            ov.z = gamma * acc[i][j][2] + xv.z;
            ov.w = gamma * acc[i][j][3] + xv.w;
            *(float4*)&out[idx] = ov;
        }
}

// ------------------------------------------------------------------ launch --
extern "C" void kernel_launch(void* const* d_in, const int* in_sizes, int n_in,
                              void* d_out, int out_size, void* d_ws, size_t ws_size,
                              hipStream_t stream) {
    const float* x     = (const float*)d_in[0];
    const float* Wf    = (const float*)d_in[1];
    const float* Wg    = (const float*)d_in[2];
    const float* Wh    = (const float*)d_in[3];
    const float* gamma = (const float*)d_in[4];
    float* out = (float*)d_out;

    char* ws = (char*)d_ws;
    short* Wt   = (short*)(ws + 0);
    short* f_fl = (short*)(ws + 163840);
    short* g_fl = (short*)(ws + 6455296);
    short* h_t  = (short*)(ws + 12746752);
    short* P    = (short*)(ws + 63078400);

    wt_kernel<<<dim3(320), dim3(256), 0, stream>>>(Wf, Wg, Wh, Wt);
    proj_kernel<<<dim3(1536), dim3(256), 0, stream>>>(x, Wt, f_fl, g_fl, h_t);
    pgen_kernel<<<dim3(16, 32), dim3(256), 0, stream>>>(f_fl, g_fl, P);
    gemm_kernel<<<dim3(6, 8, 32), dim3(256), 0, stream>>>(P, h_t, x, gamma, out);
}

// Round 4
// 415.557 us; speedup vs baseline: 1.3092x; 1.0845x over previous
//
#include <hip/hip_runtime.h>

// SelfAttentionWithLeads v4: split-P, tiled S path with deferred normalization.
// B=32, H=12, W=256, C=256, SPLIT=3 -> hs=4, N=1024, d_qk=96, d_v=768.
//
// d_ws layout (bytes), total 130,449,408 (~130.4 MB):
//   Wt   @ 0         : [320][256] bf16  (Wf|Wg|Wh transposed)     163,840
//   f_fl @ 163840    : [32][1024][96] bf16                      6,291,456
//   g_fl @ 6455296   : [32][1024][96] bf16                      6,291,456
//   h_t  @ 12746752  : [32][768][1024] bf16 (pre-transposed)   50,331,648
//   P    @ 63078400  : [32][1024][1024] bf16 exp(s-m) UNNORM   67,108,864
//   menc @ 130187264 : [32][1024] u32 encoded row max              131,072
//   lsum @ 130318336 : [32][1024] f32 row sum of exp(s-m)          131,072

typedef __bf16 bf16x8 __attribute__((ext_vector_type(8)));
typedef float f32x4 __attribute__((ext_vector_type(4)));

#define MFMA16 __builtin_amdgcn_mfma_f32_16x16x32_bf16

__device__ __forceinline__ short f2bf(float f) {
    unsigned u = __builtin_bit_cast(unsigned, f);
    u += 0x7fffu + ((u >> 16) & 1u);   // round-to-nearest-even
    return (short)(u >> 16);
}
__device__ __forceinline__ unsigned pack2bf(float a, float b) {
    return ((unsigned)(unsigned short)f2bf(a)) |
           (((unsigned)(unsigned short)f2bf(b)) << 16);
}
// monotone float -> uint encoding (for atomicMax over floats incl. negatives)
__device__ __forceinline__ unsigned encf(float f) {
    unsigned u = __builtin_bit_cast(unsigned, f);
    return ((int)u < 0) ? ~u : (u | 0x80000000u);
}
__device__ __forceinline__ float decf(unsigned u) {
    unsigned v = (u & 0x80000000u) ? (u & 0x7fffffffu) : ~u;
    return __builtin_bit_cast(float, v);
}
__device__ __forceinline__ void gload_lds16(const short* g, short* l) {
    __builtin_amdgcn_global_load_lds(
        (const __attribute__((address_space(1))) unsigned int*)g,
        (__attribute__((address_space(3))) unsigned int*)l, 16, 0, 0);
}

// ---------------------------------------------------------------- weights ---
__global__ __launch_bounds__(256) void wt_kernel(const float* __restrict__ Wf,
                                                 const float* __restrict__ Wg,
                                                 const float* __restrict__ Wh,
                                                 short* __restrict__ Wt) {
    int t = blockIdx.x * 256 + threadIdx.x;
    int j = t >> 8, k = t & 255;
    float v;
    if (j < 32)      v = Wf[k * 32 + j];
    else if (j < 64) v = Wg[k * 32 + (j - 32)];
    else             v = Wh[k * 256 + (j - 64)];
    Wt[j * 256 + k] = f2bf(v);
}

// ------------------------------------------------------------- projections --
__global__ __launch_bounds__(256) void proj_kernel(const float* __restrict__ x,
                                                   const short* __restrict__ Wt,
                                                   short* __restrict__ f_fl,
                                                   short* __restrict__ g_fl,
                                                   short* __restrict__ h_t) {
    const int tid = threadIdx.x;
    const int P0  = blockIdx.x * 64;
    const int b   = P0 / 3072;
    const int rem = P0 % 3072;
    const int hh  = rem >> 8;
    const int wbase = rem & 255;
    const int lead = hh >> 2, hsi = hh & 3;
    const int nbase = hsi * 256 + wbase;

    __shared__ __align__(16) short xs[64][264];

    const float4* xv = (const float4*)(x + (size_t)P0 * 256);
    #pragma unroll
    for (int i = 0; i < 16; ++i) {
        int idx = i * 256 + tid;
        float4 v = xv[idx];
        int pix = idx >> 6;
        int col = (idx & 63) * 4;
        *(short4*)&xs[pix][col] =
            make_short4(f2bf(v.x), f2bf(v.y), f2bf(v.z), f2bf(v.w));
    }
    __syncthreads();

    const int lane = tid & 63, wv = tid >> 6;
    const int quad = lane >> 4, l15 = lane & 15;

    // ---- phase 1: f,g (rows = channels j) ----
    {
        const int jrow = wv * 16 + l15;
        f32x4 acc[4] = {};
        #pragma unroll
        for (int ki = 0; ki < 8; ++ki) {
            bf16x8 a = *(const bf16x8*)&Wt[jrow * 256 + ki * 32 + quad * 8];
            #pragma unroll
            for (int pt = 0; pt < 4; ++pt) {
                bf16x8 bb = *(const bf16x8*)&xs[pt * 16 + l15][ki * 32 + quad * 8];
                acc[pt] = MFMA16(a, bb, acc[pt], 0, 0, 0);
            }
        }
        short* dst = (wv < 2) ? f_fl : g_fl;
        const int jloc = (wv & 1) * 16 + quad * 4;
        #pragma unroll
        for (int pt = 0; pt < 4; ++pt) {
            int n = nbase + pt * 16 + l15;
            *(short4*)&dst[((size_t)b * 1024 + n) * 96 + lead * 32 + jloc] =
                make_short4(f2bf(acc[pt][0]), f2bf(acc[pt][1]),
                            f2bf(acc[pt][2]), f2bf(acc[pt][3]));
        }
    }

    // ---- phase 2: h (rows = pixels, cols = out-channel cc) ----
    {
        f32x4 acc[4][4] = {};
        #pragma unroll
        for (int ki = 0; ki < 8; ++ki) {
            bf16x8 a[4], bb[4];
            #pragma unroll
            for (int pt = 0; pt < 4; ++pt)
                a[pt] = *(const bf16x8*)&xs[pt * 16 + l15][ki * 32 + quad * 8];
            #pragma unroll
            for (int ct = 0; ct < 4; ++ct)
                bb[ct] = *(const bf16x8*)&Wt[(64 + wv * 64 + ct * 16 + l15) * 256 + ki * 32 + quad * 8];
            #pragma unroll
            for (int pt = 0; pt < 4; ++pt)
                #pragma unroll
                for (int ct = 0; ct < 4; ++ct)
                    acc[pt][ct] = MFMA16(a[pt], bb[ct], acc[pt][ct], 0, 0, 0);
        }
        #pragma unroll
        for (int pt = 0; pt < 4; ++pt)
            #pragma unroll
            for (int ct = 0; ct < 4; ++ct) {
                int cc = wv * 64 + ct * 16 + l15;
                size_t base = ((size_t)b * 768 + lead * 256 + cc) * 1024
                              + nbase + pt * 16 + quad * 4;
                *(short4*)&h_t[base] =
                    make_short4(f2bf(acc[pt][ct][0]), f2bf(acc[pt][ct][1]),
                                f2bf(acc[pt][ct][2]), f2bf(acc[pt][ct][3]));
            }
    }
}

// ------------------------------------------------------------ S row maxes ---
// Block = 128 keys x 128 qrows of S^T = f . g^T. All frag loads up front
// (L2-hot, high ILP), 48 MFMA/wave, per-qrow max -> atomicMax(encoded).
__global__ __launch_bounds__(256) void smax_kernel(const short* __restrict__ f_fl,
                                                   const short* __restrict__ g_fl,
                                                   unsigned* __restrict__ menc) {
    const int kt = blockIdx.x, qt = blockIdx.y, b = blockIdx.z;
    const int tid = threadIdx.x, lane = tid & 63, wv = tid >> 6;
    const int quad = lane >> 4, l15 = lane & 15;
    const int wm = (wv & 1) * 64, wn = (wv >> 1) * 64;
    const short* fB = f_fl + ((size_t)b * 1024 + kt * 128 + wm) * 96;
    const short* gB = g_fl + ((size_t)b * 1024 + qt * 128 + wn) * 96;

    bf16x8 bfr[4][3];
    #pragma unroll
    for (int j = 0; j < 4; ++j)
        #pragma unroll
        for (int ki = 0; ki < 3; ++ki)
            bfr[j][ki] = *(const bf16x8*)&gB[(j * 16 + l15) * 96 + ki * 32 + quad * 8];

    f32x4 acc[4][4] = {};
    #pragma unroll
    for (int i = 0; i < 4; ++i) {
        bf16x8 a[3];
        #pragma unroll
        for (int ki = 0; ki < 3; ++ki)
            a[ki] = *(const bf16x8*)&fB[(i * 16 + l15) * 96 + ki * 32 + quad * 8];
        #pragma unroll
        for (int j = 0; j < 4; ++j)
            #pragma unroll
            for (int ki = 0; ki < 3; ++ki)
                acc[i][j] = MFMA16(a[ki], bfr[j][ki], acc[i][j], 0, 0, 0);
    }

    #pragma unroll
    for (int j = 0; j < 4; ++j) {
        float v = acc[0][j][0];
        #pragma unroll
        for (int i = 0; i < 4; ++i)
            #pragma unroll
            for (int r = 0; r < 4; ++r) v = fmaxf(v, acc[i][j][r]);
        v = fmaxf(v, __shfl_xor(v, 16));
        v = fmaxf(v, __shfl_xor(v, 32));
        if (quad == 0)
            atomicMax(&menc[b * 1024 + qt * 128 + wn + j * 16 + l15], encf(v));
    }
}

// ------------------------------------------- exp(S - m), row sums, P store --
// Recomputes S bitwise-identically to smax_kernel (same frags, same MFMA
// order), so s - m <= 0 exactly. Stores UNNORMALIZED E = exp(s-m) in bf16;
// per-qrow sums published via atomicAdd; normalization deferred to gemm.
__global__ __launch_bounds__(256) void pexp_kernel(const short* __restrict__ f_fl,
                                                   const short* __restrict__ g_fl,
                                                   const unsigned* __restrict__ menc,
                                                   float* __restrict__ lsum,
                                                   short* __restrict__ P) {
    const int kt = blockIdx.x, qt = blockIdx.y, b = blockIdx.z;
    const int tid = threadIdx.x, lane = tid & 63, wv = tid >> 6;
    const int quad = lane >> 4, l15 = lane & 15;
    const int wm = (wv & 1) * 64, wn = (wv >> 1) * 64;
    const short* fB = f_fl + ((size_t)b * 1024 + kt * 128 + wm) * 96;
    const short* gB = g_fl + ((size_t)b * 1024 + qt * 128 + wn) * 96;

    bf16x8 bfr[4][3];
    #pragma unroll
    for (int j = 0; j < 4; ++j)
        #pragma unroll
        for (int ki = 0; ki < 3; ++ki)
            bfr[j][ki] = *(const bf16x8*)&gB[(j * 16 + l15) * 96 + ki * 32 + quad * 8];

    f32x4 acc[4][4] = {};
    #pragma unroll
    for (int i = 0; i < 4; ++i) {
        bf16x8 a[3];
        #pragma unroll
        for (int ki = 0; ki < 3; ++ki)
            a[ki] = *(const bf16x8*)&fB[(i * 16 + l15) * 96 + ki * 32 + quad * 8];
        #pragma unroll
        for (int j = 0; j < 4; ++j)
            #pragma unroll
            for (int ki = 0; ki < 3; ++ki)
                acc[i][j] = MFMA16(a[ki], bfr[j][ki], acc[i][j], 0, 0, 0);
    }

    short* Pb = (short*)P + (size_t)b * 1024 * 1024;
    #pragma unroll
    for (int j = 0; j < 4; ++j) {
        const int qrow = qt * 128 + wn + j * 16 + l15;
        const float mj = decf(menc[b * 1024 + qrow]);
        float rs = 0.f;
        #pragma unroll
        for (int i = 0; i < 4; ++i) {
            float e0 = __expf(acc[i][j][0] - mj);
            float e1 = __expf(acc[i][j][1] - mj);
            float e2 = __expf(acc[i][j][2] - mj);
            float e3 = __expf(acc[i][j][3] - mj);
            rs += (e0 + e1) + (e2 + e3);
            uint2 w;
            w.x = pack2bf(e0, e1);
            w.y = pack2bf(e2, e3);
            *(uint2*)&Pb[(size_t)qrow * 1024 + kt * 128 + wm + i * 16 + quad * 4] = w;
        }
        rs += __shfl_xor(rs, 16);
        rs += __shfl_xor(rs, 32);
        if (quad == 0)
            atomicAdd(&lsum[b * 1024 + qrow], rs);
    }
}

// --------------------------------------------------------------- PV GEMM ----
// O^T = H_t * E^T per batch, scaled by 1/l[qrow] in the epilogue.
__global__ __launch_bounds__(256, 2) void gemm_kernel(const short* __restrict__ P,
                                                      const short* __restrict__ h_t,
                                                      const float* __restrict__ lsum,
                                                      const float* __restrict__ x,
                                                      const float* __restrict__ gammap,
                                                      float* __restrict__ out) {
    const int mt = blockIdx.x, nt = blockIdx.y, b = blockIdx.z;
    const int tid = threadIdx.x, lane = tid & 63, wv = tid >> 6;
    const int quad = lane >> 4, l15 = lane & 15;
    const int wm = (wv & 1) * 64, wn = (wv >> 1) * 64;

    __shared__ __align__(16) short As[128 * 32];
    __shared__ __align__(16) short Bs[128 * 32];

    const short* hB = h_t + ((size_t)b * 768 + mt * 128) * 1024;
    const short* Pb = P + ((size_t)b * 1024 + nt * 128) * 1024;

    const int srow = wv * 16 + (lane >> 2);
    const int scol = (lane & 3) * 8;
    const short* gA0 = hB + (size_t)srow * 1024 + scol;
    const short* gA1 = hB + (size_t)(srow + 64) * 1024 + scol;
    const short* gB0 = Pb + (size_t)srow * 1024 + scol;
    const short* gB1 = Pb + (size_t)(srow + 64) * 1024 + scol;
    short* lA0 = &As[srow * 32 + scol];
    short* lA1 = &As[(srow + 64) * 32 + scol];
    short* lB0 = &Bs[srow * 32 + scol];
    short* lB1 = &Bs[(srow + 64) * 32 + scol];

    f32x4 acc[4][4] = {};

    for (int kt = 0; kt < 32; ++kt) {
        const int k0 = kt * 32;
        gload_lds16(gA0 + k0, lA0);
        gload_lds16(gA1 + k0, lA1);
        gload_lds16(gB0 + k0, lB0);
        gload_lds16(gB1 + k0, lB1);
        __syncthreads();
        bf16x8 a[4], bb[4];
        #pragma unroll
        for (int i = 0; i < 4; ++i)
            a[i] = *(const bf16x8*)&As[(wm + i * 16 + l15) * 32 + quad * 8];
        #pragma unroll
        for (int j = 0; j < 4; ++j)
            bb[j] = *(const bf16x8*)&Bs[(wn + j * 16 + l15) * 32 + quad * 8];
        #pragma unroll
        for (int i = 0; i < 4; ++i)
            #pragma unroll
            for (int j = 0; j < 4; ++j)
                acc[i][j] = MFMA16(a[i], bb[j], acc[i][j], 0, 0, 0);
        __syncthreads();
    }

    const float gamma = gammap[0];
    float gl[4];
    #pragma unroll
    for (int j = 0; j < 4; ++j)
        gl[j] = gamma / lsum[b * 1024 + nt * 128 + wn + j * 16 + l15];

    #pragma unroll
    for (int i = 0; i < 4; ++i)
        #pragma unroll
        for (int j = 0; j < 4; ++j) {
            int vc = mt * 128 + wm + i * 16 + quad * 4;   // 4 consecutive channels
            int qrow = nt * 128 + wn + j * 16 + l15;
            int lead = vc >> 8, c = vc & 255;
            int hsi = qrow >> 8, w_ = qrow & 255;
            size_t idx = (((size_t)b * 12 + lead * 4 + hsi) * 256 + w_) * 256 + c;
            float4 xv = *(const float4*)&x[idx];
            float4 ov;
            ov.x = gl[j] * acc[i][j][0] + xv.x;
            ov.y = gl[j] * acc[i][j][1] + xv.y;
            ov.z = gl[j] * acc[i][j][2] + xv.z;
            ov.w = gl[j] * acc[i][j][3] + xv.w;
            *(float4*)&out[idx] = ov;
        }
}

// ------------------------------------------------------------------ launch --
extern "C" void kernel_launch(void* const* d_in, const int* in_sizes, int n_in,
                              void* d_out, int out_size, void* d_ws, size_t ws_size,
                              hipStream_t stream) {
    const float* x     = (const float*)d_in[0];
    const float* Wf    = (const float*)d_in[1];
    const float* Wg    = (const float*)d_in[2];
    const float* Wh    = (const float*)d_in[3];
    const float* gamma = (const float*)d_in[4];
    float* out = (float*)d_out;

    char* ws = (char*)d_ws;
    short*    Wt   = (short*)(ws + 0);
    short*    f_fl = (short*)(ws + 163840);
    short*    g_fl = (short*)(ws + 6455296);
    short*    h_t  = (short*)(ws + 12746752);
    short*    P    = (short*)(ws + 63078400);
    unsigned* menc = (unsigned*)(ws + 130187264);
    float*    lsum = (float*)(ws + 130318336);

    hipMemsetAsync(menc, 0, 32 * 1024 * 4, stream);
    hipMemsetAsync(lsum, 0, 32 * 1024 * 4, stream);
    wt_kernel<<<dim3(320), dim3(256), 0, stream>>>(Wf, Wg, Wh, Wt);
    proj_kernel<<<dim3(1536), dim3(256), 0, stream>>>(x, Wt, f_fl, g_fl, h_t);
    smax_kernel<<<dim3(8, 8, 32), dim3(256), 0, stream>>>(f_fl, g_fl, menc);
    pexp_kernel<<<dim3(8, 8, 32), dim3(256), 0, stream>>>(f_fl, g_fl, menc, lsum, P);
    gemm_kernel<<<dim3(6, 8, 32), dim3(256), 0, stream>>>(P, h_t, lsum, x, gamma, out);
}